// Round 1
// baseline (117.427 us; speedup 1.0000x reference)
//
#include <hip/hip_runtime.h>
#include <stdint.h>

// Problem constants (B=1, L=256, C=128, N=4, TN=4)
#define LLTOT 65536   // L*L pixels
#define CDIM  128
#define TPIX  32      // pixels per block
#define NBLK  (LLTOT / TPIX)   // 2048

typedef float f32x4 __attribute__((ext_vector_type(4)));
typedef short s16x8 __attribute__((ext_vector_type(8)));

#define MFMA16(a, b, c) __builtin_amdgcn_mfma_f32_16x16x32_bf16((a), (b), (c), 0, 0, 0)

__device__ __forceinline__ unsigned short f2bf(float f) {
    union { float f; uint32_t u; } v; v.f = f;
    uint32_t u = v.u;
    return (unsigned short)((u + 0x7FFFu + ((u >> 16) & 1u)) >> 16);
}

// ws layout (uint16 elements): Weff_b[32][128] @ 0, W1b[512][128] @ 4096, W2b[128][512] @ 69632
__global__ void prep_kernel(const float* __restrict__ Wpre, const float* __restrict__ Wpost,
                            const float* __restrict__ Wres, const float* __restrict__ W1,
                            const float* __restrict__ W2, unsigned short* __restrict__ ws16) {
    int idx = blockIdx.x * 256 + threadIdx.x;
    if (idx < 4096) {
        int o = idx >> 7, c = idx & 127;
        float v = 0.f;
        if (o < 4)        v = Wpre[o*512+c] + Wpre[o*512+128+c] + Wpre[o*512+256+c] + Wpre[o*512+384+c];
        else if (o < 8)   { int j = o - 4;  v = Wpost[j*512+c] + Wpost[j*512+128+c] + Wpost[j*512+256+c] + Wpost[j*512+384+c]; }
        else if (o < 24)  { int j = o - 8;  v = Wres[j*512+c] + Wres[j*512+128+c] + Wres[j*512+256+c] + Wres[j*512+384+c]; }
        ws16[idx] = f2bf(v);
    } else if (idx < 4096 + 65536) {
        ws16[idx] = f2bf(W1[idx - 4096]);
    } else if (idx < 4096 + 131072) {
        ws16[idx] = f2bf(W2[idx - 69632]);
    }
}

__global__ void __launch_bounds__(256) fused_kernel(
    const float* __restrict__ p, const float* __restrict__ p_mask,
    const float* __restrict__ b_pre, const float* __restrict__ b_post, const float* __restrict__ b_res,
    const float* __restrict__ a_pre, const float* __restrict__ a_post, const float* __restrict__ a_res,
    const float* __restrict__ ln_g, const float* __restrict__ ln_b,
    const float* __restrict__ b1, const float* __restrict__ b2,
    const unsigned short* __restrict__ wsb, float* __restrict__ out)
{
    __shared__ __align__(16) float          p_s[TPIX * CDIM];        // 16 KB, f32 p tile (alive all phases)
    __shared__ __align__(16) unsigned short mn_s[TPIX * CDIM];       // 8 KB, bf16: pn (ph3-4) then m_norm (ph6-7)
    __shared__ __align__(16) unsigned short h_s[TPIX * 512];         // 32 KB, bf16 relu(h)
    __shared__ __align__(16) float          pup_s[TPIX * CDIM];      // 16 KB: y_s[32][32] (ph4-5) then GEMM2 D (ph8-9)
    __shared__ __align__(16) float b1_s[512];
    __shared__ __align__(16) float b2_s[CDIM], lng_s[CDIM], lnb_s[CDIM];
    __shared__ float mask_s[TPIX];
    __shared__ float rms_s[TPIX], mean_s[TPIX], var_s[TPIX], spre_s[TPIX];
    __shared__ float hpost_s[TPIX * 4], r_s[TPIX * 4];
    __shared__ float bpre_s[4], bpost_s[4], bres_s[16];

    const int t = threadIdx.x;
    const int base = blockIdx.x * TPIX;

    // ---- phase 1: stage p tile + small params ----
    {
        const float4* pg = (const float4*)(p + (size_t)base * CDIM);
        float4* ps4 = (float4*)p_s;
        #pragma unroll
        for (int q = 0; q < 4; ++q) ps4[t + q * 256] = pg[t + q * 256];
        if (t < 128) ((float4*)b1_s)[t] = ((const float4*)b1)[t];
        if (t < 32) {
            ((float4*)b2_s)[t]  = ((const float4*)b2)[t];
            ((float4*)lng_s)[t] = ((const float4*)ln_g)[t];
            ((float4*)lnb_s)[t] = ((const float4*)ln_b)[t];
            mask_s[t] = p_mask[base + t];
        }
        if (t < 16) bres_s[t] = b_res[t];
        if (t < 4)  { bpre_s[t] = b_pre[t]; bpost_s[t] = b_post[t]; }
    }
    __syncthreads();

    // ---- phase 2: per-pixel sum / sumsq (8 threads per pixel) ----
    {
        int pix = t >> 3, part = t & 7;
        const float4* row = (const float4*)(p_s + pix * CDIM) + part * 4;
        float s = 0.f, ss = 0.f;
        #pragma unroll
        for (int q = 0; q < 4; ++q) {
            float4 v = row[q];
            s  += v.x + v.y + v.z + v.w;
            ss += v.x*v.x + v.y*v.y + v.z*v.z + v.w*v.w;
        }
        s += __shfl_xor(s, 1); ss += __shfl_xor(ss, 1);
        s += __shfl_xor(s, 2); ss += __shfl_xor(ss, 2);
        s += __shfl_xor(s, 4); ss += __shfl_xor(ss, 4);
        if (part == 0) {
            float mq = ss * (1.f / 128.f);
            float mu = s  * (1.f / 128.f);
            rms_s[pix]  = rsqrtf(mq + 1.1920929e-07f);   // mean(xf^2) over 512 == sumsq/128
            mean_s[pix] = mu;
            var_s[pix]  = mq - mu * mu;
        }
    }
    __syncthreads();

    // ---- phase 3: pn = p * rms -> bf16, XOR-swizzled [32][128] ----
    #pragma unroll
    for (int q = 0; q < 2; ++q) {
        int chunk = t + q * 256;               // 512 chunks of 8 bf16
        int pix = chunk >> 4, c0 = (chunk & 15) << 3;
        float r = rms_s[pix];
        const float* pr = p_s + pix * CDIM + c0;
        uint32_t w0 = f2bf(pr[0]*r) | ((uint32_t)f2bf(pr[1]*r) << 16);
        uint32_t w1 = f2bf(pr[2]*r) | ((uint32_t)f2bf(pr[3]*r) << 16);
        uint32_t w2 = f2bf(pr[4]*r) | ((uint32_t)f2bf(pr[5]*r) << 16);
        uint32_t w3 = f2bf(pr[6]*r) | ((uint32_t)f2bf(pr[7]*r) << 16);
        uint32_t off = (uint32_t)(pix * 256 + c0 * 2) ^ ((pix & 7) << 4);
        *(uint4*)((char*)mn_s + off) = make_uint4(w0, w1, w2, w3);
    }
    __syncthreads();

    // ---- phase 4: routing mini-GEMM y[24+pad, 32] = Weff[32,128] @ pn^T (wave 0 only) ----
    if (t < 64) {
        int lr = t & 15, lk = t >> 4;
        f32x4 acc[2][2] = {};
        #pragma unroll
        for (int kk = 0; kk < 4; ++kk) {
            s16x8 bfr[2];
            #pragma unroll
            for (int it = 0; it < 2; ++it) {
                int row = it * 16 + lr;
                uint32_t off = (uint32_t)(row * 256 + kk * 64 + lk * 16) ^ ((row & 7) << 4);
                bfr[it] = *(const s16x8*)((const char*)mn_s + off);
            }
            #pragma unroll
            for (int jt = 0; jt < 2; ++jt) {
                int o = jt * 16 + lr;
                s16x8 a = *(const s16x8*)((const char*)wsb + o * 256 + kk * 64 + lk * 16);
                acc[jt][0] = MFMA16(a, bfr[0], acc[jt][0]);
                acc[jt][1] = MFMA16(a, bfr[1], acc[jt][1]);
            }
        }
        float* y_s = pup_s;   // [32 pix][32 outs]
        #pragma unroll
        for (int jt = 0; jt < 2; ++jt)
            #pragma unroll
            for (int it = 0; it < 2; ++it) {
                int pix = it * 16 + lr;
                int o0 = jt * 16 + lk * 4;
                *(f32x4*)(y_s + pix * 32 + o0) = acc[jt][it];
            }
    }
    __syncthreads();

    // ---- phase 5: activations + Sinkhorn (4 lanes per pixel, threads < 128) ----
    if (t < 128) {
        const float* y_s = pup_s;
        int pix = t >> 2, m = t & 3;
        float apre = a_pre[0], apost = a_post[0], ares = a_res[0];
        const float* yp = y_s + pix * 32;
        float hpre = 1.f / (1.f + expf(-(apre * tanhf(yp[m]) + bpre_s[m])));
        float sp = hpre;
        sp += __shfl_xor(sp, 1); sp += __shfl_xor(sp, 2);
        if (m == 0) spre_s[pix] = sp;
        hpost_s[pix * 4 + m] = 2.f / (1.f + expf(-(apost * tanhf(yp[4 + m]) + bpost_s[m])));
        float M0 = expf(ares * tanhf(yp[8 + m * 4 + 0]) + bres_s[m * 4 + 0]);
        float M1 = expf(ares * tanhf(yp[8 + m * 4 + 1]) + bres_s[m * 4 + 1]);
        float M2 = expf(ares * tanhf(yp[8 + m * 4 + 2]) + bres_s[m * 4 + 2]);
        float M3 = expf(ares * tanhf(yp[8 + m * 4 + 3]) + bres_s[m * 4 + 3]);
        #pragma unroll 1
        for (int it = 0; it < 20; ++it) {
            float ri = __builtin_amdgcn_rcpf(M0 + M1 + M2 + M3);   // row normalize
            M0 *= ri; M1 *= ri; M2 *= ri; M3 *= ri;
            float c0 = M0, c1 = M1, c2 = M2, c3 = M3;              // col sums across 4 lanes
            c0 += __shfl_xor(c0, 1); c1 += __shfl_xor(c1, 1); c2 += __shfl_xor(c2, 1); c3 += __shfl_xor(c3, 1);
            c0 += __shfl_xor(c0, 2); c1 += __shfl_xor(c1, 2); c2 += __shfl_xor(c2, 2); c3 += __shfl_xor(c3, 2);
            M0 *= __builtin_amdgcn_rcpf(c0); M1 *= __builtin_amdgcn_rcpf(c1);
            M2 *= __builtin_amdgcn_rcpf(c2); M3 *= __builtin_amdgcn_rcpf(c3);
        }
        r_s[pix * 4 + m] = M0 + M1 + M2 + M3;   // row sums of final doubly-stochastic M
    }
    __syncthreads();

    // ---- phase 6: m_norm = LN(s_pre * p) -> bf16, swizzled (overwrites pn) ----
    #pragma unroll
    for (int q = 0; q < 2; ++q) {
        int chunk = t + q * 256;
        int pix = chunk >> 4, c0 = (chunk & 15) << 3;
        float sp = spre_s[pix];
        float mu = sp * mean_s[pix];
        float istd = rsqrtf(sp * sp * var_s[pix] + 1e-5f);
        const float* pr = p_s + pix * CDIM + c0;
        uint32_t w[4];
        #pragma unroll
        for (int j = 0; j < 4; ++j) {
            float v0 = (sp * pr[2*j]   - mu) * istd * lng_s[c0 + 2*j]   + lnb_s[c0 + 2*j];
            float v1 = (sp * pr[2*j+1] - mu) * istd * lng_s[c0 + 2*j+1] + lnb_s[c0 + 2*j+1];
            w[j] = f2bf(v0) | ((uint32_t)f2bf(v1) << 16);
        }
        uint32_t off = (uint32_t)(pix * 256 + c0 * 2) ^ ((pix & 7) << 4);
        *(uint4*)((char*)mn_s + off) = make_uint4(w[0], w[1], w[2], w[3]);
    }
    __syncthreads();

    // ---- phase 7: GEMM1  h[j,i] = relu(W1[j,:] . mn[i,:] + b1[j]) -> bf16 h_s[i][j] swizzled ----
    {
        int w = t >> 6, l = t & 63;
        int lr = l & 15, lk = l >> 4;
        const unsigned short* W1b = wsb + 4096;   // [512][128] bf16
        f32x4 acc[8][2] = {};
        #pragma unroll
        for (int kk = 0; kk < 4; ++kk) {
            s16x8 bfr[2];
            #pragma unroll
            for (int it = 0; it < 2; ++it) {
                int row = it * 16 + lr;
                uint32_t off = (uint32_t)(row * 256 + kk * 64 + lk * 16) ^ ((row & 7) << 4);
                bfr[it] = *(const s16x8*)((const char*)mn_s + off);
            }
            #pragma unroll
            for (int j8 = 0; j8 < 8; ++j8) {
                int j = (w * 8 + j8) * 16 + lr;
                s16x8 a = *(const s16x8*)((const char*)W1b + j * 256 + kk * 64 + lk * 16);
                acc[j8][0] = MFMA16(a, bfr[0], acc[j8][0]);
                acc[j8][1] = MFMA16(a, bfr[1], acc[j8][1]);
            }
        }
        #pragma unroll
        for (int j8 = 0; j8 < 8; ++j8) {
            int j0 = (w * 8 + j8) * 16 + lk * 4;
            float bb0 = b1_s[j0], bb1 = b1_s[j0+1], bb2 = b1_s[j0+2], bb3 = b1_s[j0+3];
            #pragma unroll
            for (int it = 0; it < 2; ++it) {
                int i = it * 16 + lr;
                f32x4 v = acc[j8][it];
                uint32_t u01 = f2bf(fmaxf(v[0] + bb0, 0.f)) | ((uint32_t)f2bf(fmaxf(v[1] + bb1, 0.f)) << 16);
                uint32_t u23 = f2bf(fmaxf(v[2] + bb2, 0.f)) | ((uint32_t)f2bf(fmaxf(v[3] + bb3, 0.f)) << 16);
                uint32_t off = (uint32_t)(i * 1024 + j0 * 2) ^ ((i & 7) << 4);
                *(uint2*)((char*)h_s + off) = make_uint2(u01, u23);
            }
        }
    }
    __syncthreads();

    // ---- phase 8: GEMM2  D[c,i] = W2[c,:] . h[i,:]  -> f32 pup_s[i][c] swizzled ----
    {
        int w = t >> 6, l = t & 63;
        int lr = l & 15, lk = l >> 4;
        const unsigned short* W2b = wsb + 69632;  // [128][512] bf16
        f32x4 acc[2][2] = {};
        for (int kk = 0; kk < 16; ++kk) {
            s16x8 bfr[2];
            #pragma unroll
            for (int it = 0; it < 2; ++it) {
                int i = it * 16 + lr;
                uint32_t off = (uint32_t)(i * 1024 + kk * 64 + lk * 16) ^ ((i & 7) << 4);
                bfr[it] = *(const s16x8*)((const char*)h_s + off);
            }
            #pragma unroll
            for (int ct = 0; ct < 2; ++ct) {
                int c = (w * 2 + ct) * 16 + lr;
                s16x8 a = *(const s16x8*)((const char*)W2b + c * 1024 + kk * 64 + lk * 16);
                acc[ct][0] = MFMA16(a, bfr[0], acc[ct][0]);
                acc[ct][1] = MFMA16(a, bfr[1], acc[ct][1]);
            }
        }
        #pragma unroll
        for (int ct = 0; ct < 2; ++ct) {
            int c0 = (w * 2 + ct) * 16 + lk * 4;
            #pragma unroll
            for (int it = 0; it < 2; ++it) {
                int i = it * 16 + lr;
                uint32_t off = (uint32_t)(i * 512 + c0 * 4) ^ ((i & 7) << 4);
                *(f32x4*)((char*)pup_s + off) = acc[ct][it];
            }
        }
    }
    __syncthreads();

    // ---- phase 9: epilogue  out[i,m,c] = r[m]*p[c] + H_post[m]*(s_pre*p[c] + (D+b2)*mask) ----
    {
        float4* og = (float4*)(out + (size_t)base * 512);
        #pragma unroll 4
        for (int q = 0; q < 16; ++q) {
            int idx = t + q * 256;            // 4096 float4s per block
            int pix = idx >> 7;
            int rem = idx & 127;
            int m = rem >> 5;
            int c0 = (rem & 31) << 2;
            float4 p4 = *(const float4*)(p_s + pix * CDIM + c0);
            uint32_t off = (uint32_t)(pix * 512 + c0 * 4) ^ ((pix & 7) << 4);
            f32x4 d4 = *(const f32x4*)((const char*)pup_s + off);
            float msk = mask_s[pix], sp = spre_s[pix];
            float rr = r_s[pix * 4 + m], hp = hpost_s[pix * 4 + m];
            float4 o;
            o.x = rr * p4.x + hp * (sp * p4.x + (d4[0] + b2_s[c0+0]) * msk);
            o.y = rr * p4.y + hp * (sp * p4.y + (d4[1] + b2_s[c0+1]) * msk);
            o.z = rr * p4.z + hp * (sp * p4.z + (d4[2] + b2_s[c0+2]) * msk);
            o.w = rr * p4.w + hp * (sp * p4.w + (d4[3] + b2_s[c0+3]) * msk);
            og[idx] = o;
        }
    }
}

extern "C" void kernel_launch(void* const* d_in, const int* in_sizes, int n_in,
                              void* d_out, int out_size, void* d_ws, size_t ws_size,
                              hipStream_t stream) {
    const float* p      = (const float*)d_in[0];
    const float* p_mask = (const float*)d_in[1];
    const float* W_pre  = (const float*)d_in[2];
    const float* W_post = (const float*)d_in[3];
    const float* W_res  = (const float*)d_in[4];
    const float* b_pre  = (const float*)d_in[5];
    const float* b_post = (const float*)d_in[6];
    const float* b_res  = (const float*)d_in[7];
    const float* a_pre  = (const float*)d_in[8];
    const float* a_post = (const float*)d_in[9];
    const float* a_res  = (const float*)d_in[10];
    const float* ln_g   = (const float*)d_in[11];
    const float* ln_b   = (const float*)d_in[12];
    const float* W1     = (const float*)d_in[13];
    const float* b1     = (const float*)d_in[14];
    const float* W2     = (const float*)d_in[15];
    const float* b2     = (const float*)d_in[16];
    unsigned short* wsb = (unsigned short*)d_ws;
    float* out = (float*)d_out;

    prep_kernel<<<528, 256, 0, stream>>>(W_pre, W_post, W_res, W1, W2, wsb);
    fused_kernel<<<NBLK, 256, 0, stream>>>(p, p_mask, b_pre, b_post, b_res,
                                           a_pre, a_post, a_res, ln_g, ln_b,
                                           b1, b2, wsb, out);
}